// Round 14
// baseline (1156.050 us; speedup 1.0000x reference)
//
#include <hip/hip_runtime.h>
#include <stdint.h>

constexpr int kN    = 100000;   // nodes
constexpr int kDOut = 128;      // output dim
constexpr int kDIn  = 256;      // input feature dim
constexpr int kNNZ  = 3200000;  // nnz for both X and A
constexpr float kInvKeep = (float)(1.0 / 0.9);
constexpr int kCopies = 8;      // XCD privatization (proven r11/r13)
constexpr int kRPB    = 4;      // rows per bucket
constexpr int kNBkt   = kN / kRPB;   // 25000 (exact)

// ---------------- RNG (verified round 4: partitionable, bits = o0^o1) -----
__device__ __forceinline__ uint32_t rotl32(uint32_t v, int r) {
  return (v << r) | (v >> (32 - r));
}
__device__ __forceinline__ void threefry2x32(uint32_t k0, uint32_t k1,
                                             uint32_t x0, uint32_t x1,
                                             uint32_t& o0, uint32_t& o1) {
  const uint32_t ks0 = k0, ks1 = k1, ks2 = k0 ^ k1 ^ 0x1BD11BDAu;
  x0 += ks0; x1 += ks1;
#define TF_RND(r) { x0 += x1; x1 = rotl32(x1, (r)); x1 ^= x0; }
  TF_RND(13) TF_RND(15) TF_RND(26) TF_RND(6)
  x0 += ks1; x1 += ks2 + 1u;
  TF_RND(17) TF_RND(29) TF_RND(16) TF_RND(24)
  x0 += ks2; x1 += ks0 + 2u;
  TF_RND(13) TF_RND(15) TF_RND(26) TF_RND(6)
  x0 += ks0; x1 += ks1 + 3u;
  TF_RND(17) TF_RND(29) TF_RND(16) TF_RND(24)
  x0 += ks1; x1 += ks2 + 4u;
  TF_RND(13) TF_RND(15) TF_RND(26) TF_RND(6)
  x0 += ks2; x1 += ks0 + 5u;
#undef TF_RND
  o0 = x0; o1 = x1;
}
__device__ __forceinline__ float keep_mask(uint32_t i) {
  uint32_t o0, o1;
  threefry2x32(0u, 42u, 0u, i, o0, o1);
  uint32_t bits = o0 ^ o1;
  float u = __uint_as_float((bits >> 9) | 0x3f800000u) - 1.0f;
  return floorf(0.9f + u);
}

// ---------------- bf16 helpers (RTNE) --------------------------------------
__device__ __forceinline__ uint32_t f32_to_bf16(float f) {
  uint32_t u = __float_as_uint(f);
  u += 0x7fffu + ((u >> 16) & 1u);
  return u >> 16;
}
__device__ __forceinline__ float bf16lo_to_f32(uint32_t packed) {
  return __uint_as_float(packed << 16);
}
__device__ __forceinline__ float bf16hi_to_f32(uint32_t packed) {
  return __uint_as_float(packed & 0xffff0000u);
}

// ---------------- W pack: f32 [256][128] -> bf16 [256][128] ---------------
__global__ void wpack_kernel(const float* __restrict__ W, uint32_t* __restrict__ Wp) {
  int i = blockIdx.x * blockDim.x + threadIdx.x;   // pair index
  if (i >= kDIn * (kDOut / 2)) return;
  float w0 = W[2 * i], w1 = W[2 * i + 1];
  Wp[i] = f32_to_bf16(w0) | (f32_to_bf16(w1) << 16);
}

// ---------------- bucket histogram, XCD-privatized -------------------------
template<bool DROPOUT>
__global__ void hist8b_kernel(const int* __restrict__ rows, int* __restrict__ bcnt8,
                              int nnz) {
  int e = blockIdx.x * blockDim.x + threadIdx.x;
  if (e >= nnz) return;
  if (DROPOUT && keep_mask((uint32_t)e) == 0.0f) return;
  int k = blockIdx.x & (kCopies - 1);
  atomicAdd(&bcnt8[k * kNBkt + (rows[e] >> 2)], 1);
}

// ---------------- scan over summed copies (bucket granularity) -------------
constexpr int kScanChunk = 2048;   // 256 threads x 8 elems
constexpr int kScanBlkB  = (kNBkt + kScanChunk - 1) / kScanChunk;  // 13

__global__ void scan1_kernel(const int* __restrict__ cnt8, int* __restrict__ ptr,
                             int* __restrict__ partials, int n) {
  __shared__ int sd[256];
  int b = blockIdx.x, t = threadIdx.x;
  int base = b * kScanChunk + t * 8;
  int v[8]; int s = 0;
  #pragma unroll
  for (int k = 0; k < 8; ++k) {
    int idx = base + k;
    int c = 0;
    if (idx < n) {
      #pragma unroll
      for (int j = 0; j < kCopies; ++j) c += cnt8[j * n + idx];
    }
    v[k] = c; s += c;
  }
  sd[t] = s; __syncthreads();
  #pragma unroll
  for (int off = 1; off < 256; off <<= 1) {
    int x = (t >= off) ? sd[t - off] : 0;
    __syncthreads();
    sd[t] += x;
    __syncthreads();
  }
  if (t == 255) partials[b] = sd[255];
  int run = (t == 0) ? 0 : sd[t - 1];
  #pragma unroll
  for (int k = 0; k < 8; ++k) { int idx = base + k; if (idx < n) ptr[idx] = run; run += v[k]; }
}

__global__ void scan2_kernel(int* __restrict__ partials, int* __restrict__ ptr,
                             int nblk, int n) {
  __shared__ int sd[64];
  int t = threadIdx.x;
  sd[t] = (t < nblk) ? partials[t] : 0;
  __syncthreads();
  #pragma unroll
  for (int off = 1; off < 64; off <<= 1) {
    int x = (t >= off) ? sd[t - off] : 0;
    __syncthreads();
    sd[t] += x;
    __syncthreads();
  }
  if (t < nblk) partials[t] = (t == 0) ? 0 : sd[t - 1];
  if (t == 63) ptr[n] = sd[63];
}

// finalize bptr; emit per-copy cursors bcur8[k][b] = bptr[b] + prefix_k
__global__ void scan3b_kernel(int* __restrict__ bptr, int* __restrict__ bcur8,
                              const int* __restrict__ bcnt8,
                              const int* __restrict__ partials, int n) {
  int i = blockIdx.x * blockDim.x + threadIdx.x;
  if (i >= n) return;
  int v = bptr[i] + partials[i / kScanChunk];
  bptr[i] = v;
  int run = v;
  #pragma unroll
  for (int k = 0; k < kCopies; ++k) {
    bcur8[k * n + i] = run;
    run += bcnt8[k * n + i];
  }
}

// ---------------- bucket scatter, XCD-local cursors AND data lines ---------
// record: p.x = (row&3)<<17 | col (col < 2^17), p.y = f32 val bits.
// Per-(bucket,copy) sub-segment avg 16 edges = 128B >= line -> one XCD/line.
template<bool DROPOUT>
__global__ void bscatter_kernel(const int* __restrict__ rows,
                                const int* __restrict__ cols,
                                const float* __restrict__ vals,
                                int* __restrict__ bcur8,
                                uint2* __restrict__ spack, int nnz) {
  int e = blockIdx.x * blockDim.x + threadIdx.x;
  if (e >= nnz) return;
  float v = vals[e];
  if (DROPOUT) {
    if (keep_mask((uint32_t)e) == 0.0f) return;
    v *= kInvKeep;
  }
  int r = rows[e];
  int k = blockIdx.x & (kCopies - 1);
  int pos = atomicAdd(&bcur8[k * kNBkt + (r >> 2)], 1);
  uint2 p;
  p.x = ((uint32_t)(r & 3) << 17) | (uint32_t)cols[e];
  p.y = __float_as_uint(v);
  spack[pos] = p;
}

// ---------------- bucket SpMM: wave per bucket, 4 register acc-pairs -------
// rl = p.x>>17 is wave-uniform per edge (all 64 lanes read the same edge) ->
// the 4-way branch is exec-mask cheap. No LDS, no FP atomics.
template<bool OUT_BF16, bool RELU>
__global__ void bspmm_kernel(const int* __restrict__ bptr,
                             const uint2* __restrict__ spack,
                             const uint16_t* __restrict__ B,   // bf16 [*, kDOut]
                             void* __restrict__ outv) {
  const int tid = threadIdx.x;
  const int b = blockIdx.x * 4 + (tid >> 6);   // kNBkt % 4 == 0
  const int lane = tid & 63;
  const int dof = 2 * lane;
  int e = bptr[b], end = bptr[b + 1];
  float a00 = 0.f, a01 = 0.f, a10 = 0.f, a11 = 0.f;
  float a20 = 0.f, a21 = 0.f, a30 = 0.f, a31 = 0.f;

  auto acc = [&](uint2 p, uint32_t g) {
    float v  = __uint_as_float(p.y);
    float lo = bf16lo_to_f32(g), hi = bf16hi_to_f32(g);
    uint32_t rl = p.x >> 17;
    if (rl == 0)      { a00 += v * lo; a01 += v * hi; }
    else if (rl == 1) { a10 += v * lo; a11 += v * hi; }
    else if (rl == 2) { a20 += v * lo; a21 += v * hi; }
    else              { a30 += v * lo; a31 += v * hi; }
  };

  for (; e + 3 < end; e += 4) {
    uint2 p0 = spack[e],     p1 = spack[e + 1];
    uint2 p2 = spack[e + 2], p3 = spack[e + 3];
    uint32_t g0 = *(const uint32_t*)(B + (size_t)(p0.x & 0x1FFFFu) * kDOut + dof);
    uint32_t g1 = *(const uint32_t*)(B + (size_t)(p1.x & 0x1FFFFu) * kDOut + dof);
    uint32_t g2 = *(const uint32_t*)(B + (size_t)(p2.x & 0x1FFFFu) * kDOut + dof);
    uint32_t g3 = *(const uint32_t*)(B + (size_t)(p3.x & 0x1FFFFu) * kDOut + dof);
    acc(p0, g0); acc(p1, g1); acc(p2, g2); acc(p3, g3);
  }
  for (; e < end; ++e) {
    uint2 p0 = spack[e];
    uint32_t g0 = *(const uint32_t*)(B + (size_t)(p0.x & 0x1FFFFu) * kDOut + dof);
    acc(p0, g0);
  }

  const size_t rowbase = (size_t)b * kRPB;
  auto emit = [&](int j, float x0, float x1) {
    if (RELU) { x0 = fmaxf(x0, 0.0f); x1 = fmaxf(x1, 0.0f); }
    if (OUT_BF16) {
      uint32_t pk = f32_to_bf16(x0) | (f32_to_bf16(x1) << 16);
      ((uint32_t*)outv)[(rowbase + j) * (kDOut / 2) + lane] = pk;
    } else {
      float2 f; f.x = x0; f.y = x1;
      ((float2*)outv)[(rowbase + j) * (kDOut / 2) + lane] = f;
    }
  };
  emit(0, a00, a01); emit(1, a10, a11); emit(2, a20, a21); emit(3, a30, a31);
}

// ---------------------------------------------------------------------------
extern "C" void kernel_launch(void* const* d_in, const int* in_sizes, int n_in,
                              void* d_out, int out_size, void* d_ws, size_t ws_size,
                              hipStream_t stream) {
  const int*   x_rows   = (const int*)d_in[0];
  const int*   x_cols   = (const int*)d_in[1];
  const float* x_vals   = (const float*)d_in[2];
  const int*   adj_rows = (const int*)d_in[3];
  const int*   adj_cols = (const int*)d_in[4];
  const float* adj_vals = (const float*)d_in[5];
  const float* W        = (const float*)d_in[6];
  float* out = (float*)d_out;

  // workspace layout (256B-aligned chunks)
  size_t off = 0;
  auto take = [&](size_t bytes) -> char* {
    char* p = (char*)d_ws + off;
    off += (bytes + 255) & ~(size_t)255;
    return p;
  };
  uint16_t* hb     = (uint16_t*)take((size_t)kN * kDOut * 2);         // 25.6 MB
  uint32_t* Wp     = (uint32_t*)take((size_t)kDIn * (kDOut / 2) * 4); // 64 KB
  int*      bptr   = (int*)take((size_t)(kNBkt + 1) * 4);             // 100 KB
  int*      bcnt8  = (int*)take((size_t)kCopies * kNBkt * 4);         // 800 KB
  int*      bcur8  = (int*)take((size_t)kCopies * kNBkt * 4);         // 800 KB
  int*      partials = (int*)take(64 * 4);
  uint2*    spack  = (uint2*)take((size_t)kNNZ * 8);                  // 25.6 MB
  const size_t needed = off;                                          // ~53 MB
  if (ws_size < needed) return;  // ws proven >= 157 MB (r12 ran dense path)

  const int edgeBlocks  = (kNNZ + 255) / 256;
  const int scan3Blocks = (kNBkt + 255) / 256;
  const int spmmBlocks  = kNBkt / 4;   // 6250

  wpack_kernel<<<(kDIn * (kDOut / 2) + 255) / 256, 256, 0, stream>>>(W, Wp);

  // ---------- X: bucket-CSR build (dropout folded) + bspmm1 -> hb ----------
  hipMemsetAsync(bcnt8, 0, (size_t)kCopies * kNBkt * 4, stream);
  hist8b_kernel<true><<<edgeBlocks, 256, 0, stream>>>(x_rows, bcnt8, kNNZ);
  scan1_kernel<<<kScanBlkB, 256, 0, stream>>>(bcnt8, bptr, partials, kNBkt);
  scan2_kernel<<<1, 64, 0, stream>>>(partials, bptr, kScanBlkB, kNBkt);
  scan3b_kernel<<<scan3Blocks, 256, 0, stream>>>(bptr, bcur8, bcnt8, partials, kNBkt);
  bscatter_kernel<true><<<edgeBlocks, 256, 0, stream>>>(
      x_rows, x_cols, x_vals, bcur8, spack, kNNZ);
  bspmm_kernel<true, false><<<spmmBlocks, 256, 0, stream>>>(
      bptr, spack, (const uint16_t*)Wp, hb);

  // ---------- adj: bucket-CSR build + bspmm2(+relu) -> out ----------
  hipMemsetAsync(bcnt8, 0, (size_t)kCopies * kNBkt * 4, stream);
  hist8b_kernel<false><<<edgeBlocks, 256, 0, stream>>>(adj_rows, bcnt8, kNNZ);
  scan1_kernel<<<kScanBlkB, 256, 0, stream>>>(bcnt8, bptr, partials, kNBkt);
  scan2_kernel<<<1, 64, 0, stream>>>(partials, bptr, kScanBlkB, kNBkt);
  scan3b_kernel<<<scan3Blocks, 256, 0, stream>>>(bptr, bcur8, bcnt8, partials, kNBkt);
  bscatter_kernel<false><<<edgeBlocks, 256, 0, stream>>>(
      adj_rows, adj_cols, adj_vals, bcur8, spack, kNNZ);
  bspmm_kernel<false, true><<<spmmBlocks, 256, 0, stream>>>(
      bptr, spack, hb, out);
}

// Round 15
// 894.417 us; speedup vs baseline: 1.2925x; 1.2925x over previous
//
#include <hip/hip_runtime.h>
#include <hip/hip_fp16.h>
#include <stdint.h>

constexpr int kN    = 100000;   // nodes
constexpr int kDOut = 128;      // output dim
constexpr int kDIn  = 256;      // input feature dim
constexpr int kNNZ  = 3200000;  // nnz for both X and A
constexpr float kInvKeep = (float)(1.0 / 0.9);
constexpr int kCopies = 8;      // XCD privatization (proven r11/r13)

// ---------------- RNG (verified round 4: partitionable, bits = o0^o1) -----
__device__ __forceinline__ uint32_t rotl32(uint32_t v, int r) {
  return (v << r) | (v >> (32 - r));
}
__device__ __forceinline__ void threefry2x32(uint32_t k0, uint32_t k1,
                                             uint32_t x0, uint32_t x1,
                                             uint32_t& o0, uint32_t& o1) {
  const uint32_t ks0 = k0, ks1 = k1, ks2 = k0 ^ k1 ^ 0x1BD11BDAu;
  x0 += ks0; x1 += ks1;
#define TF_RND(r) { x0 += x1; x1 = rotl32(x1, (r)); x1 ^= x0; }
  TF_RND(13) TF_RND(15) TF_RND(26) TF_RND(6)
  x0 += ks1; x1 += ks2 + 1u;
  TF_RND(17) TF_RND(29) TF_RND(16) TF_RND(24)
  x0 += ks2; x1 += ks0 + 2u;
  TF_RND(13) TF_RND(15) TF_RND(26) TF_RND(6)
  x0 += ks0; x1 += ks1 + 3u;
  TF_RND(17) TF_RND(29) TF_RND(16) TF_RND(24)
  x0 += ks1; x1 += ks2 + 4u;
  TF_RND(13) TF_RND(15) TF_RND(26) TF_RND(6)
  x0 += ks2; x1 += ks0 + 5u;
#undef TF_RND
  o0 = x0; o1 = x1;
}
__device__ __forceinline__ float keep_mask(uint32_t i) {
  uint32_t o0, o1;
  threefry2x32(0u, 42u, 0u, i, o0, o1);
  uint32_t bits = o0 ^ o1;
  float u = __uint_as_float((bits >> 9) | 0x3f800000u) - 1.0f;
  return floorf(0.9f + u);
}

// ---------------- bf16 helpers (RTNE) --------------------------------------
__device__ __forceinline__ uint32_t f32_to_bf16(float f) {
  uint32_t u = __float_as_uint(f);
  u += 0x7fffu + ((u >> 16) & 1u);
  return u >> 16;
}
__device__ __forceinline__ float bf16lo_to_f32(uint32_t packed) {
  return __uint_as_float(packed << 16);
}
__device__ __forceinline__ float bf16hi_to_f32(uint32_t packed) {
  return __uint_as_float(packed & 0xffff0000u);
}

// ---------------- W pack: f32 [256][128] -> bf16 [256][128] ---------------
__global__ void wpack_kernel(const float* __restrict__ W, uint32_t* __restrict__ Wp) {
  int i = blockIdx.x * blockDim.x + threadIdx.x;   // pair index
  if (i >= kDIn * (kDOut / 2)) return;
  float w0 = W[2 * i], w1 = W[2 * i + 1];
  Wp[i] = f32_to_bf16(w0) | (f32_to_bf16(w1) << 16);
}

// ---------------- X dense path: scatter-add + skinny GEMM ------------------
__global__ void scatteradd_kernel(const int* __restrict__ rows,
                                  const int* __restrict__ cols,
                                  const float* __restrict__ vals,
                                  float* __restrict__ Xd, int nnz) {
  int e = blockIdx.x * blockDim.x + threadIdx.x;
  if (e >= nnz) return;
  if (keep_mask((uint32_t)e) == 0.0f) return;
  atomicAdd(&Xd[(size_t)rows[e] * kDIn + cols[e]], vals[e] * kInvKeep);
}

// 1024 threads = 16 waves = 16 rows/block (proven r13).
// NEW: wave-uniform zero-quad skip -- X density 11% => 62% of float4 quads
// are all-zero and xp[q] is identical across the wave's 64 lanes, so the
// branch is uniform (no divergence). Saves unpack+FMA VALU work.
__global__ void __launch_bounds__(1024) gemm_kernel(const float* __restrict__ Xd,
                                                    const uint32_t* __restrict__ Wp,
                                                    uint32_t* __restrict__ hb) {
  __shared__ uint32_t wl[kDIn * (kDOut / 2)];   // 16384 u32 = 64 KB
  const int tid = threadIdx.x;
  #pragma unroll
  for (int i = 0; i < 16; ++i) wl[i * 1024 + tid] = Wp[i * 1024 + tid];
  __syncthreads();
  const int row  = blockIdx.x * 16 + (tid >> 6);   // kN % 16 == 0
  const int lane = tid & 63;
  const float4* xp = (const float4*)(Xd + (size_t)row * kDIn);
  float a0 = 0.0f, a1 = 0.0f;
  for (int q = 0; q < kDIn / 4; q += 2) {
    float4 xA = xp[q];
    float4 xB = xp[q + 1];
    if (!(xA.x == 0.f && xA.y == 0.f && xA.z == 0.f && xA.w == 0.f)) {
      uint32_t g0 = wl[(4 * q + 0) * 64 + lane];
      uint32_t g1 = wl[(4 * q + 1) * 64 + lane];
      uint32_t g2 = wl[(4 * q + 2) * 64 + lane];
      uint32_t g3 = wl[(4 * q + 3) * 64 + lane];
      a0 += xA.x * bf16lo_to_f32(g0); a1 += xA.x * bf16hi_to_f32(g0);
      a0 += xA.y * bf16lo_to_f32(g1); a1 += xA.y * bf16hi_to_f32(g1);
      a0 += xA.z * bf16lo_to_f32(g2); a1 += xA.z * bf16hi_to_f32(g2);
      a0 += xA.w * bf16lo_to_f32(g3); a1 += xA.w * bf16hi_to_f32(g3);
    }
    if (!(xB.x == 0.f && xB.y == 0.f && xB.z == 0.f && xB.w == 0.f)) {
      uint32_t g4 = wl[(4 * q + 4) * 64 + lane];
      uint32_t g5 = wl[(4 * q + 5) * 64 + lane];
      uint32_t g6 = wl[(4 * q + 6) * 64 + lane];
      uint32_t g7 = wl[(4 * q + 7) * 64 + lane];
      a0 += xB.x * bf16lo_to_f32(g4); a1 += xB.x * bf16hi_to_f32(g4);
      a0 += xB.y * bf16lo_to_f32(g5); a1 += xB.y * bf16hi_to_f32(g5);
      a0 += xB.z * bf16lo_to_f32(g6); a1 += xB.z * bf16hi_to_f32(g6);
      a0 += xB.w * bf16lo_to_f32(g7); a1 += xB.w * bf16hi_to_f32(g7);
    }
  }
  hb[(size_t)row * 64 + lane] = f32_to_bf16(a0) | (f32_to_bf16(a1) << 16);
}

// ---------------- XCD-privatized histogram (proven round 11/13) ------------
__global__ void hist8_kernel(const int* __restrict__ rows, int* __restrict__ cnt8,
                             int nnz) {
  int e = blockIdx.x * blockDim.x + threadIdx.x;
  if (e >= nnz) return;
  int k = blockIdx.x & (kCopies - 1);
  atomicAdd(&cnt8[k * kN + rows[e]], 1);
}

// ---------------- scan over summed copies ----------------------------------
constexpr int kScanChunk = 2048;   // 256 threads x 8 elems
constexpr int kScanBlk   = (kN + kScanChunk - 1) / kScanChunk;  // 49

__global__ void scan1_kernel(const int* __restrict__ cnt8, int* __restrict__ rowptr,
                             int* __restrict__ partials, int n) {
  __shared__ int sd[256];
  int b = blockIdx.x, t = threadIdx.x;
  int base = b * kScanChunk + t * 8;
  int v[8]; int s = 0;
  #pragma unroll
  for (int k = 0; k < 8; ++k) {
    int idx = base + k;
    int c = 0;
    if (idx < n) {
      #pragma unroll
      for (int j = 0; j < kCopies; ++j) c += cnt8[j * kN + idx];
    }
    v[k] = c; s += c;
  }
  sd[t] = s; __syncthreads();
  #pragma unroll
  for (int off = 1; off < 256; off <<= 1) {
    int x = (t >= off) ? sd[t - off] : 0;
    __syncthreads();
    sd[t] += x;
    __syncthreads();
  }
  if (t == 255) partials[b] = sd[255];
  int run = (t == 0) ? 0 : sd[t - 1];
  #pragma unroll
  for (int k = 0; k < 8; ++k) { int idx = base + k; if (idx < n) rowptr[idx] = run; run += v[k]; }
}

__global__ void scan2_kernel(int* __restrict__ partials, int* __restrict__ rowptr,
                             int nblk, int n) {
  __shared__ int sd[64];
  int t = threadIdx.x;
  sd[t] = (t < nblk) ? partials[t] : 0;
  __syncthreads();
  #pragma unroll
  for (int off = 1; off < 64; off <<= 1) {
    int x = (t >= off) ? sd[t - off] : 0;
    __syncthreads();
    sd[t] += x;
    __syncthreads();
  }
  if (t < nblk) partials[t] = (t == 0) ? 0 : sd[t - 1];
  if (t == 63) rowptr[n] = sd[63];
}

__global__ void scan3_kernel(int* __restrict__ rowptr, int* __restrict__ cur,
                             const int* __restrict__ partials, int n) {
  int i = blockIdx.x * blockDim.x + threadIdx.x;
  if (i < n) {
    int v = rowptr[i] + partials[i / kScanChunk];
    rowptr[i] = v;
    cur[i] = v;
  }
}

// ---------------- single-cursor scatter, 4-BYTE records --------------------
// adj record: col (17 bits) << 15 | fp16 bits sans sign (vals positive).
// Halves scatter write traffic AND spmm's spack stream vs the 8B record.
__global__ void scatter_adj_kernel(const int* __restrict__ rows,
                                   const int* __restrict__ cols,
                                   const float* __restrict__ vals,
                                   int* __restrict__ cur,
                                   uint32_t* __restrict__ spack, int nnz) {
  int e = blockIdx.x * blockDim.x + threadIdx.x;
  if (e >= nnz) return;
  float v = vals[e];
  int pos = atomicAdd(&cur[rows[e]], 1);
  uint32_t h = (uint32_t)__half_as_ushort(__float2half_rn(v)) & 0x7FFFu;
  spack[pos] = ((uint32_t)cols[e] << 15) | h;
}

// ---------------- CSR SpMM over 4B records, 8-deep unroll ------------------
// 4 rows per 256-thread block; 64 lanes/row; record broadcast-loaded by the
// wave, lane computes d=2*lane, 2*lane+1 via one bf16x2 gather per edge.
template<bool RELU>
__global__ void spmm_csr_kernel(const int* __restrict__ rowptr,
                                const uint32_t* __restrict__ spack,
                                const uint16_t* __restrict__ B,  // bf16 [*, kDOut]
                                float* __restrict__ outv, int nrows) {
  int tid = threadIdx.x;
  int row = blockIdx.x * 4 + (tid >> 6);
  int lane = tid & 63;
  if (row >= nrows) return;
  int e = rowptr[row], e_end = rowptr[row + 1];
  float a0 = 0.0f, a1 = 0.0f;
  const int doff = lane * 2;
  auto dec = [](uint32_t p) -> float {
    return __half2float(__ushort_as_half((unsigned short)(p & 0x7FFFu)));
  };
  for (; e + 7 < e_end; e += 8) {
    uint32_t p0 = spack[e],     p1 = spack[e + 1];
    uint32_t p2 = spack[e + 2], p3 = spack[e + 3];
    uint32_t p4 = spack[e + 4], p5 = spack[e + 5];
    uint32_t p6 = spack[e + 6], p7 = spack[e + 7];
    uint32_t g0 = *(const uint32_t*)(B + (size_t)(p0 >> 15) * kDOut + doff);
    uint32_t g1 = *(const uint32_t*)(B + (size_t)(p1 >> 15) * kDOut + doff);
    uint32_t g2 = *(const uint32_t*)(B + (size_t)(p2 >> 15) * kDOut + doff);
    uint32_t g3 = *(const uint32_t*)(B + (size_t)(p3 >> 15) * kDOut + doff);
    uint32_t g4 = *(const uint32_t*)(B + (size_t)(p4 >> 15) * kDOut + doff);
    uint32_t g5 = *(const uint32_t*)(B + (size_t)(p5 >> 15) * kDOut + doff);
    uint32_t g6 = *(const uint32_t*)(B + (size_t)(p6 >> 15) * kDOut + doff);
    uint32_t g7 = *(const uint32_t*)(B + (size_t)(p7 >> 15) * kDOut + doff);
    float v0 = dec(p0), v1 = dec(p1), v2 = dec(p2), v3 = dec(p3);
    float v4 = dec(p4), v5 = dec(p5), v6 = dec(p6), v7 = dec(p7);
    a0 += v0 * bf16lo_to_f32(g0); a1 += v0 * bf16hi_to_f32(g0);
    a0 += v1 * bf16lo_to_f32(g1); a1 += v1 * bf16hi_to_f32(g1);
    a0 += v2 * bf16lo_to_f32(g2); a1 += v2 * bf16hi_to_f32(g2);
    a0 += v3 * bf16lo_to_f32(g3); a1 += v3 * bf16hi_to_f32(g3);
    a0 += v4 * bf16lo_to_f32(g4); a1 += v4 * bf16hi_to_f32(g4);
    a0 += v5 * bf16lo_to_f32(g5); a1 += v5 * bf16hi_to_f32(g5);
    a0 += v6 * bf16lo_to_f32(g6); a1 += v6 * bf16hi_to_f32(g6);
    a0 += v7 * bf16lo_to_f32(g7); a1 += v7 * bf16hi_to_f32(g7);
  }
  for (; e < e_end; ++e) {
    uint32_t p0 = spack[e];
    float v0 = dec(p0);
    uint32_t g0 = *(const uint32_t*)(B + (size_t)(p0 >> 15) * kDOut + doff);
    a0 += v0 * bf16lo_to_f32(g0);
    a1 += v0 * bf16hi_to_f32(g0);
  }
  if (RELU) { a0 = fmaxf(a0, 0.0f); a1 = fmaxf(a1, 0.0f); }
  float2 o; o.x = a0; o.y = a1;
  ((float2*)outv)[(size_t)row * (kDOut / 2) + lane] = o;
}

// ---------------------------------------------------------------------------
extern "C" void kernel_launch(void* const* d_in, const int* in_sizes, int n_in,
                              void* d_out, int out_size, void* d_ws, size_t ws_size,
                              hipStream_t stream) {
  const int*   x_rows   = (const int*)d_in[0];
  const int*   x_cols   = (const int*)d_in[1];
  const float* x_vals   = (const float*)d_in[2];
  const int*   adj_rows = (const int*)d_in[3];
  const int*   adj_cols = (const int*)d_in[4];
  const float* adj_vals = (const float*)d_in[5];
  const float* W        = (const float*)d_in[6];
  float* out = (float*)d_out;

  // workspace layout (256B-aligned chunks)
  size_t off = 0;
  auto take = [&](size_t bytes) -> char* {
    char* p = (char*)d_ws + off;
    off += (bytes + 255) & ~(size_t)255;
    return p;
  };
  uint16_t* hb     = (uint16_t*)take((size_t)kN * kDOut * 2);         // 25.6 MB
  uint32_t* Wp     = (uint32_t*)take((size_t)kDIn * (kDOut / 2) * 4); // 64 KB
  int*      rowptr = (int*)take((size_t)(kN + 1) * 4);                // 400 KB
  int*      cnt8   = (int*)take((size_t)kCopies * kN * 4);            // 3.2 MB
  int*      cur    = (int*)take((size_t)kN * 4);                      // 400 KB
  int*      partials = (int*)take(64 * 4);
  uint32_t* spack  = (uint32_t*)take((size_t)kNNZ * 4);               // 12.8 MB
  float*    Xd     = (float*)take((size_t)kN * kDIn * 4);             // 102.4 MB
  const size_t needed = off;                                          // ~145 MB
  if (ws_size < needed) return;  // ws proven >= 157.7 MB (r12/r13 dense path ran)

  const int edgeBlocks = (kNNZ + 255) / 256;
  const int spmmBlocks = (kN + 3) / 4;

  wpack_kernel<<<(kDIn * (kDOut / 2) + 255) / 256, 256, 0, stream>>>(W, Wp);

  // ---------- X: dense scatter-add + LDS-W gemm (proven r13) -> hb ----------
  hipMemsetAsync(Xd, 0, (size_t)kN * kDIn * 4, stream);
  scatteradd_kernel<<<edgeBlocks, 256, 0, stream>>>(x_rows, x_cols, x_vals, Xd, kNNZ);
  gemm_kernel<<<kN / 16, 1024, 0, stream>>>(Xd, Wp, (uint32_t*)hb);

  // ---------- adj: CSR (hist8 + single-cur 4B scatter) + spmm2(+relu) ------
  hipMemsetAsync(cnt8, 0, (size_t)kCopies * kN * 4, stream);
  hist8_kernel<<<edgeBlocks, 256, 0, stream>>>(adj_rows, cnt8, kNNZ);
  scan1_kernel<<<kScanBlk, 256, 0, stream>>>(cnt8, rowptr, partials, kN);
  scan2_kernel<<<1, 64, 0, stream>>>(partials, rowptr, kScanBlk, kN);
  scan3_kernel<<<(kN + 255) / 256, 256, 0, stream>>>(rowptr, cur, partials, kN);
  scatter_adj_kernel<<<edgeBlocks, 256, 0, stream>>>(
      adj_rows, adj_cols, adj_vals, cur, spack, kNNZ);
  spmm_csr_kernel<true><<<spmmBlocks, 256, 0, stream>>>(
      rowptr, spack, hb, out, kN);
}

// Round 16
// 668.863 us; speedup vs baseline: 1.7284x; 1.3372x over previous
//
#include <hip/hip_runtime.h>
#include <hip/hip_fp16.h>
#include <stdint.h>

constexpr int kN    = 100000;   // nodes
constexpr int kDOut = 128;      // output dim
constexpr int kDIn  = 256;      // input feature dim
constexpr int kNNZ  = 3200000;  // nnz for both X and A
constexpr float kInvKeep = (float)(1.0 / 0.9);
constexpr int kCopies = 8;      // XCD privatization (proven r11/r13)

typedef __attribute__((ext_vector_type(8))) short short8v;  // 8 bf16 (4 VGPR)
typedef __attribute__((ext_vector_type(4))) float f32x4;    // MFMA C/D

// ---------------- RNG (verified round 4: partitionable, bits = o0^o1) -----
__device__ __forceinline__ uint32_t rotl32(uint32_t v, int r) {
  return (v << r) | (v >> (32 - r));
}
__device__ __forceinline__ void threefry2x32(uint32_t k0, uint32_t k1,
                                             uint32_t x0, uint32_t x1,
                                             uint32_t& o0, uint32_t& o1) {
  const uint32_t ks0 = k0, ks1 = k1, ks2 = k0 ^ k1 ^ 0x1BD11BDAu;
  x0 += ks0; x1 += ks1;
#define TF_RND(r) { x0 += x1; x1 = rotl32(x1, (r)); x1 ^= x0; }
  TF_RND(13) TF_RND(15) TF_RND(26) TF_RND(6)
  x0 += ks1; x1 += ks2 + 1u;
  TF_RND(17) TF_RND(29) TF_RND(16) TF_RND(24)
  x0 += ks2; x1 += ks0 + 2u;
  TF_RND(13) TF_RND(15) TF_RND(26) TF_RND(6)
  x0 += ks0; x1 += ks1 + 3u;
  TF_RND(17) TF_RND(29) TF_RND(16) TF_RND(24)
  x0 += ks1; x1 += ks2 + 4u;
  TF_RND(13) TF_RND(15) TF_RND(26) TF_RND(6)
  x0 += ks2; x1 += ks0 + 5u;
#undef TF_RND
  o0 = x0; o1 = x1;
}
__device__ __forceinline__ float keep_mask(uint32_t i) {
  uint32_t o0, o1;
  threefry2x32(0u, 42u, 0u, i, o0, o1);
  uint32_t bits = o0 ^ o1;
  float u = __uint_as_float((bits >> 9) | 0x3f800000u) - 1.0f;
  return floorf(0.9f + u);
}

// ---------------- bf16 helpers (RTNE) --------------------------------------
__device__ __forceinline__ uint32_t f32_to_bf16(float f) {
  uint32_t u = __float_as_uint(f);
  u += 0x7fffu + ((u >> 16) & 1u);
  return u >> 16;
}
__device__ __forceinline__ float bf16lo_to_f32(uint32_t packed) {
  return __uint_as_float(packed << 16);
}
__device__ __forceinline__ float bf16hi_to_f32(uint32_t packed) {
  return __uint_as_float(packed & 0xffff0000u);
}

// ---------------- W -> MFMA B-fragment order -------------------------------
// For (ntile, kstep): 1KB block; lane l holds 8 bf16 at col n=ntile*16+(l&15),
// k = kstep*32 + (l>>4)*8 + j  (B: col=lane&15, k=(lane>>4)*8+j).
// u32 index: nt*2048 + ks*256 + lane*4 + jj, packing j=2jj (lo), 2jj+1 (hi).
__global__ void wpack_frag_kernel(const float* __restrict__ W,
                                  uint32_t* __restrict__ Wt) {
  int i = blockIdx.x * blockDim.x + threadIdx.x;
  if (i >= kDIn * kDOut / 2) return;   // 16384
  int jj   = i & 3;
  int lane = (i >> 2) & 63;
  int ks   = (i >> 8) & 7;
  int nt   = i >> 11;
  int n = nt * 16 + (lane & 15);
  int k = ks * 32 + ((lane >> 4) * 8) + 2 * jj;
  uint32_t lo = f32_to_bf16(W[(size_t)k * kDOut + n]);
  uint32_t hi = f32_to_bf16(W[(size_t)(k + 1) * kDOut + n]);
  Wt[i] = lo | (hi << 16);
}

// ---------------- X dense path: scatter-add + MFMA GEMM --------------------
__global__ void scatteradd_kernel(const int* __restrict__ rows,
                                  const int* __restrict__ cols,
                                  const float* __restrict__ vals,
                                  float* __restrict__ Xd, int nnz) {
  int e = blockIdx.x * blockDim.x + threadIdx.x;
  if (e >= nnz) return;
  if (keep_mask((uint32_t)e) == 0.0f) return;
  atomicAdd(&Xd[(size_t)rows[e] * kDIn + cols[e]], vals[e] * kInvKeep);
}

// Wave computes 16 rows x 128 cols: 8 ksteps x 8 ntile MFMAs (16x16x32 bf16).
// A: row = lane&15, k = (lane>>4)*8+j (cvt f32->bf16 in flight).
// B: fragment-ordered Wt, 16B/lane coalesced, 64KB L1-resident.
// D: col = lane&15, row = (lane>>4)*4+reg (m89-verified).
__global__ void __launch_bounds__(256) gemm_mfma_kernel(
    const float* __restrict__ Xd, const uint32_t* __restrict__ Wt,
    uint16_t* __restrict__ hb) {
  const int tid = threadIdx.x;
  const int gw = blockIdx.x * 4 + (tid >> 6);
  if (gw >= kN / 16) return;
  const int lane = tid & 63;
  const int row16 = gw * 16;
  const float* xrow = Xd + (size_t)(row16 + (lane & 15)) * kDIn + ((lane >> 4) * 8);

  f32x4 acc[8];
  #pragma unroll
  for (int nt = 0; nt < 8; ++nt) acc[nt] = f32x4{0.f, 0.f, 0.f, 0.f};

  #pragma unroll
  for (int ks = 0; ks < 8; ++ks) {
    float4 xa = *(const float4*)(xrow + ks * 32);
    float4 xb = *(const float4*)(xrow + ks * 32 + 4);
    short8v a;
    a[0] = (short)f32_to_bf16(xa.x); a[1] = (short)f32_to_bf16(xa.y);
    a[2] = (short)f32_to_bf16(xa.z); a[3] = (short)f32_to_bf16(xa.w);
    a[4] = (short)f32_to_bf16(xb.x); a[5] = (short)f32_to_bf16(xb.y);
    a[6] = (short)f32_to_bf16(xb.z); a[7] = (short)f32_to_bf16(xb.w);
    const uint32_t* bbase = Wt + ks * 256 + lane * 4;
    #pragma unroll
    for (int nt = 0; nt < 8; ++nt) {
      short8v b = *(const short8v*)(bbase + nt * 2048);
      acc[nt] = __builtin_amdgcn_mfma_f32_16x16x32_bf16(a, b, acc[nt], 0, 0, 0);
    }
  }

  const int r0 = row16 + (lane >> 4) * 4;
  const int c0 = lane & 15;
  #pragma unroll
  for (int nt = 0; nt < 8; ++nt) {
    #pragma unroll
    for (int rg = 0; rg < 4; ++rg) {
      hb[(size_t)(r0 + rg) * kDOut + nt * 16 + c0] =
          (uint16_t)f32_to_bf16(acc[nt][rg]);
    }
  }
}

// ---------------- XCD-privatized histogram (proven r11/r13) ----------------
__global__ void hist8_kernel(const int* __restrict__ rows, int* __restrict__ cnt8,
                             int nnz) {
  int e = blockIdx.x * blockDim.x + threadIdx.x;
  if (e >= nnz) return;
  int k = blockIdx.x & (kCopies - 1);
  atomicAdd(&cnt8[k * kN + rows[e]], 1);
}

// ---------------- scan over summed copies ----------------------------------
constexpr int kScanChunk = 2048;   // 256 threads x 8 elems
constexpr int kScanBlk   = (kN + kScanChunk - 1) / kScanChunk;  // 49

__global__ void scan1_kernel(const int* __restrict__ cnt8, int* __restrict__ rowptr,
                             int* __restrict__ partials, int n) {
  __shared__ int sd[256];
  int b = blockIdx.x, t = threadIdx.x;
  int base = b * kScanChunk + t * 8;
  int v[8]; int s = 0;
  #pragma unroll
  for (int k = 0; k < 8; ++k) {
    int idx = base + k;
    int c = 0;
    if (idx < n) {
      #pragma unroll
      for (int j = 0; j < kCopies; ++j) c += cnt8[j * kN + idx];
    }
    v[k] = c; s += c;
  }
  sd[t] = s; __syncthreads();
  #pragma unroll
  for (int off = 1; off < 256; off <<= 1) {
    int x = (t >= off) ? sd[t - off] : 0;
    __syncthreads();
    sd[t] += x;
    __syncthreads();
  }
  if (t == 255) partials[b] = sd[255];
  int run = (t == 0) ? 0 : sd[t - 1];
  #pragma unroll
  for (int k = 0; k < 8; ++k) { int idx = base + k; if (idx < n) rowptr[idx] = run; run += v[k]; }
}

__global__ void scan2_kernel(int* __restrict__ partials, int* __restrict__ rowptr,
                             int nblk, int n) {
  __shared__ int sd[64];
  int t = threadIdx.x;
  sd[t] = (t < nblk) ? partials[t] : 0;
  __syncthreads();
  #pragma unroll
  for (int off = 1; off < 64; off <<= 1) {
    int x = (t >= off) ? sd[t - off] : 0;
    __syncthreads();
    sd[t] += x;
    __syncthreads();
  }
  if (t < nblk) partials[t] = (t == 0) ? 0 : sd[t - 1];
  if (t == 63) rowptr[n] = sd[63];
}

__global__ void scan3_kernel(int* __restrict__ rowptr, int* __restrict__ cur,
                             const int* __restrict__ partials, int n) {
  int i = blockIdx.x * blockDim.x + threadIdx.x;
  if (i < n) {
    int v = rowptr[i] + partials[i / kScanChunk];
    rowptr[i] = v;
    cur[i] = v;
  }
}

// ---------------- single-cursor scatter, 4-BYTE records (r15) --------------
// record: col(17b) << 15 | fp16 bits sans sign (adj_vals positive).
__global__ void scatter_adj_kernel(const int* __restrict__ rows,
                                   const int* __restrict__ cols,
                                   const float* __restrict__ vals,
                                   int* __restrict__ cur,
                                   uint32_t* __restrict__ spack, int nnz) {
  int e = blockIdx.x * blockDim.x + threadIdx.x;
  if (e >= nnz) return;
  float v = vals[e];
  int pos = atomicAdd(&cur[rows[e]], 1);
  uint32_t h = (uint32_t)__half_as_ushort(__float2half_rn(v)) & 0x7FFFu;
  spack[pos] = ((uint32_t)cols[e] << 15) | h;
}

// ---------------- CSR SpMM over 4B records, 8-deep unroll (r15) ------------
template<bool RELU>
__global__ void spmm_csr_kernel(const int* __restrict__ rowptr,
                                const uint32_t* __restrict__ spack,
                                const uint16_t* __restrict__ B,  // bf16 [*, kDOut]
                                float* __restrict__ outv, int nrows) {
  int tid = threadIdx.x;
  int row = blockIdx.x * 4 + (tid >> 6);
  int lane = tid & 63;
  if (row >= nrows) return;
  int e = rowptr[row], e_end = rowptr[row + 1];
  float a0 = 0.0f, a1 = 0.0f;
  const int doff = lane * 2;
  auto dec = [](uint32_t p) -> float {
    return __half2float(__ushort_as_half((unsigned short)(p & 0x7FFFu)));
  };
  for (; e + 7 < e_end; e += 8) {
    uint32_t p0 = spack[e],     p1 = spack[e + 1];
    uint32_t p2 = spack[e + 2], p3 = spack[e + 3];
    uint32_t p4 = spack[e + 4], p5 = spack[e + 5];
    uint32_t p6 = spack[e + 6], p7 = spack[e + 7];
    uint32_t g0 = *(const uint32_t*)(B + (size_t)(p0 >> 15) * kDOut + doff);
    uint32_t g1 = *(const uint32_t*)(B + (size_t)(p1 >> 15) * kDOut + doff);
    uint32_t g2 = *(const uint32_t*)(B + (size_t)(p2 >> 15) * kDOut + doff);
    uint32_t g3 = *(const uint32_t*)(B + (size_t)(p3 >> 15) * kDOut + doff);
    uint32_t g4 = *(const uint32_t*)(B + (size_t)(p4 >> 15) * kDOut + doff);
    uint32_t g5 = *(const uint32_t*)(B + (size_t)(p5 >> 15) * kDOut + doff);
    uint32_t g6 = *(const uint32_t*)(B + (size_t)(p6 >> 15) * kDOut + doff);
    uint32_t g7 = *(const uint32_t*)(B + (size_t)(p7 >> 15) * kDOut + doff);
    float v0 = dec(p0), v1 = dec(p1), v2 = dec(p2), v3 = dec(p3);
    float v4 = dec(p4), v5 = dec(p5), v6 = dec(p6), v7 = dec(p7);
    a0 += v0 * bf16lo_to_f32(g0); a1 += v0 * bf16hi_to_f32(g0);
    a0 += v1 * bf16lo_to_f32(g1); a1 += v1 * bf16hi_to_f32(g1);
    a0 += v2 * bf16lo_to_f32(g2); a1 += v2 * bf16hi_to_f32(g2);
    a0 += v3 * bf16lo_to_f32(g3); a1 += v3 * bf16hi_to_f32(g3);
    a0 += v4 * bf16lo_to_f32(g4); a1 += v4 * bf16hi_to_f32(g4);
    a0 += v5 * bf16lo_to_f32(g5); a1 += v5 * bf16hi_to_f32(g5);
    a0 += v6 * bf16lo_to_f32(g6); a1 += v6 * bf16hi_to_f32(g6);
    a0 += v7 * bf16lo_to_f32(g7); a1 += v7 * bf16hi_to_f32(g7);
  }
  for (; e < e_end; ++e) {
    uint32_t p0 = spack[e];
    float v0 = dec(p0);
    uint32_t g0 = *(const uint32_t*)(B + (size_t)(p0 >> 15) * kDOut + doff);
    a0 += v0 * bf16lo_to_f32(g0);
    a1 += v0 * bf16hi_to_f32(g0);
  }
  if (RELU) { a0 = fmaxf(a0, 0.0f); a1 = fmaxf(a1, 0.0f); }
  float2 o; o.x = a0; o.y = a1;
  ((float2*)outv)[(size_t)row * (kDOut / 2) + lane] = o;
}

// ---------------------------------------------------------------------------
extern "C" void kernel_launch(void* const* d_in, const int* in_sizes, int n_in,
                              void* d_out, int out_size, void* d_ws, size_t ws_size,
                              hipStream_t stream) {
  const int*   x_rows   = (const int*)d_in[0];
  const int*   x_cols   = (const int*)d_in[1];
  const float* x_vals   = (const float*)d_in[2];
  const int*   adj_rows = (const int*)d_in[3];
  const int*   adj_cols = (const int*)d_in[4];
  const float* adj_vals = (const float*)d_in[5];
  const float* W        = (const float*)d_in[6];
  float* out = (float*)d_out;

  // workspace layout (256B-aligned chunks)
  size_t off = 0;
  auto take = [&](size_t bytes) -> char* {
    char* p = (char*)d_ws + off;
    off += (bytes + 255) & ~(size_t)255;
    return p;
  };
  uint16_t* hb     = (uint16_t*)take((size_t)kN * kDOut * 2);         // 25.6 MB
  uint32_t* Wt     = (uint32_t*)take((size_t)kDIn * kDOut / 2 * 4);   // 64 KB
  int*      rowptr = (int*)take((size_t)(kN + 1) * 4);                // 400 KB
  int*      cnt8   = (int*)take((size_t)kCopies * kN * 4);            // 3.2 MB
  int*      cur    = (int*)take((size_t)kN * 4);                      // 400 KB
  int*      partials = (int*)take(64 * 4);
  uint32_t* spack  = (uint32_t*)take((size_t)kNNZ * 4);               // 12.8 MB
  float*    Xd     = (float*)take((size_t)kN * kDIn * 4);             // 102.4 MB
  const size_t needed = off;                                          // ~145 MB
  if (ws_size < needed) return;  // ws proven >= 157.7 MB (r12-r15 ran this path)

  const int edgeBlocks = (kNNZ + 255) / 256;
  const int spmmBlocks = (kN + 3) / 4;
  const int gemmBlocks = (kN / 16 + 3) / 4;   // 1563

  wpack_frag_kernel<<<(kDIn * kDOut / 2 + 255) / 256, 256, 0, stream>>>(W, Wt);

  // ---------- X: dense scatter-add + MFMA gemm -> hb (bf16) ----------
  hipMemsetAsync(Xd, 0, (size_t)kN * kDIn * 4, stream);
  scatteradd_kernel<<<edgeBlocks, 256, 0, stream>>>(x_rows, x_cols, x_vals, Xd, kNNZ);
  gemm_mfma_kernel<<<gemmBlocks, 256, 0, stream>>>(Xd, Wt, hb);

  // ---------- adj: CSR (hist8 + single-cur 4B scatter) + spmm2(+relu) ------
  hipMemsetAsync(cnt8, 0, (size_t)kCopies * kN * 4, stream);
  hist8_kernel<<<edgeBlocks, 256, 0, stream>>>(adj_rows, cnt8, kNNZ);
  scan1_kernel<<<kScanBlk, 256, 0, stream>>>(cnt8, rowptr, partials, kN);
  scan2_kernel<<<1, 64, 0, stream>>>(partials, rowptr, kScanBlk, kN);
  scan3_kernel<<<(kN + 255) / 256, 256, 0, stream>>>(rowptr, cur, partials, kN);
  scatter_adj_kernel<<<edgeBlocks, 256, 0, stream>>>(
      adj_rows, adj_cols, adj_vals, cur, spack, kNNZ);
  spmm_csr_kernel<true><<<spmmBlocks, 256, 0, stream>>>(
      rowptr, spack, hb, out, kN);
}

// Round 17
// 625.309 us; speedup vs baseline: 1.8488x; 1.0697x over previous
//
#include <hip/hip_runtime.h>
#include <hip/hip_fp16.h>
#include <stdint.h>

constexpr int kN    = 100000;   // nodes
constexpr int kDOut = 128;      // output dim
constexpr int kDIn  = 256;      // input feature dim
constexpr int kNNZ  = 3200000;  // nnz for both X and A
constexpr float kInvKeep = (float)(1.0 / 0.9);
constexpr int kCopies  = 8;     // XCD privatization (proven r11/r13)
constexpr int kBktRows = kN / 8;   // 12500 rows per coarse bucket

typedef __attribute__((ext_vector_type(8))) short short8v;  // 8 bf16 (4 VGPR)
typedef __attribute__((ext_vector_type(4))) float f32x4;    // MFMA C/D

// ---------------- RNG (verified round 4: partitionable, bits = o0^o1) -----
__device__ __forceinline__ uint32_t rotl32(uint32_t v, int r) {
  return (v << r) | (v >> (32 - r));
}
__device__ __forceinline__ void threefry2x32(uint32_t k0, uint32_t k1,
                                             uint32_t x0, uint32_t x1,
                                             uint32_t& o0, uint32_t& o1) {
  const uint32_t ks0 = k0, ks1 = k1, ks2 = k0 ^ k1 ^ 0x1BD11BDAu;
  x0 += ks0; x1 += ks1;
#define TF_RND(r) { x0 += x1; x1 = rotl32(x1, (r)); x1 ^= x0; }
  TF_RND(13) TF_RND(15) TF_RND(26) TF_RND(6)
  x0 += ks1; x1 += ks2 + 1u;
  TF_RND(17) TF_RND(29) TF_RND(16) TF_RND(24)
  x0 += ks2; x1 += ks0 + 2u;
  TF_RND(13) TF_RND(15) TF_RND(26) TF_RND(6)
  x0 += ks0; x1 += ks1 + 3u;
  TF_RND(17) TF_RND(29) TF_RND(16) TF_RND(24)
  x0 += ks1; x1 += ks2 + 4u;
  TF_RND(13) TF_RND(15) TF_RND(26) TF_RND(6)
  x0 += ks2; x1 += ks0 + 5u;
#undef TF_RND
  o0 = x0; o1 = x1;
}
__device__ __forceinline__ float keep_mask(uint32_t i) {
  uint32_t o0, o1;
  threefry2x32(0u, 42u, 0u, i, o0, o1);
  uint32_t bits = o0 ^ o1;
  float u = __uint_as_float((bits >> 9) | 0x3f800000u) - 1.0f;
  return floorf(0.9f + u);
}

// ---------------- bf16 helpers (RTNE) --------------------------------------
__device__ __forceinline__ uint32_t f32_to_bf16(float f) {
  uint32_t u = __float_as_uint(f);
  u += 0x7fffu + ((u >> 16) & 1u);
  return u >> 16;
}
__device__ __forceinline__ float bf16lo_to_f32(uint32_t packed) {
  return __uint_as_float(packed << 16);
}
__device__ __forceinline__ float bf16hi_to_f32(uint32_t packed) {
  return __uint_as_float(packed & 0xffff0000u);
}

// ---------------- W -> MFMA B-fragment order (verified r16) ----------------
__global__ void wpack_frag_kernel(const float* __restrict__ W,
                                  uint32_t* __restrict__ Wt) {
  int i = blockIdx.x * blockDim.x + threadIdx.x;
  if (i >= kDIn * kDOut / 2) return;   // 16384
  int jj   = i & 3;
  int lane = (i >> 2) & 63;
  int ks   = (i >> 8) & 7;
  int nt   = i >> 11;
  int n = nt * 16 + (lane & 15);
  int k = ks * 32 + ((lane >> 4) * 8) + 2 * jj;
  uint32_t lo = f32_to_bf16(W[(size_t)k * kDOut + n]);
  uint32_t hi = f32_to_bf16(W[(size_t)(k + 1) * kDOut + n]);
  Wt[i] = lo | (hi << 16);
}

// ---------------- X dense path: scatter-add + MFMA GEMM (verified r16) -----
__global__ void scatteradd_kernel(const int* __restrict__ rows,
                                  const int* __restrict__ cols,
                                  const float* __restrict__ vals,
                                  float* __restrict__ Xd, int nnz) {
  int e = blockIdx.x * blockDim.x + threadIdx.x;
  if (e >= nnz) return;
  if (keep_mask((uint32_t)e) == 0.0f) return;
  atomicAdd(&Xd[(size_t)rows[e] * kDIn + cols[e]], vals[e] * kInvKeep);
}

__global__ void __launch_bounds__(256) gemm_mfma_kernel(
    const float* __restrict__ Xd, const uint32_t* __restrict__ Wt,
    uint16_t* __restrict__ hb) {
  const int tid = threadIdx.x;
  const int gw = blockIdx.x * 4 + (tid >> 6);
  if (gw >= kN / 16) return;
  const int lane = tid & 63;
  const int row16 = gw * 16;
  const float* xrow = Xd + (size_t)(row16 + (lane & 15)) * kDIn + ((lane >> 4) * 8);

  f32x4 acc[8];
  #pragma unroll
  for (int nt = 0; nt < 8; ++nt) acc[nt] = f32x4{0.f, 0.f, 0.f, 0.f};

  #pragma unroll
  for (int ks = 0; ks < 8; ++ks) {
    float4 xa = *(const float4*)(xrow + ks * 32);
    float4 xb = *(const float4*)(xrow + ks * 32 + 4);
    short8v a;
    a[0] = (short)f32_to_bf16(xa.x); a[1] = (short)f32_to_bf16(xa.y);
    a[2] = (short)f32_to_bf16(xa.z); a[3] = (short)f32_to_bf16(xa.w);
    a[4] = (short)f32_to_bf16(xb.x); a[5] = (short)f32_to_bf16(xb.y);
    a[6] = (short)f32_to_bf16(xb.z); a[7] = (short)f32_to_bf16(xb.w);
    const uint32_t* bbase = Wt + ks * 256 + lane * 4;
    #pragma unroll
    for (int nt = 0; nt < 8; ++nt) {
      short8v b = *(const short8v*)(bbase + nt * 2048);
      acc[nt] = __builtin_amdgcn_mfma_f32_16x16x32_bf16(a, b, acc[nt], 0, 0, 0);
    }
  }

  const int r0 = row16 + (lane >> 4) * 4;
  const int c0 = lane & 15;
  #pragma unroll
  for (int nt = 0; nt < 8; ++nt) {
    #pragma unroll
    for (int rg = 0; rg < 4; ++rg) {
      hb[(size_t)(r0 + rg) * kDOut + nt * 16 + c0] =
          (uint16_t)f32_to_bf16(acc[nt][rg]);
    }
  }
}

// ---------------- XCD-privatized histogram (proven r11/r13) ----------------
__global__ void hist8_kernel(const int* __restrict__ rows, int* __restrict__ cnt8,
                             int nnz) {
  int e = blockIdx.x * blockDim.x + threadIdx.x;
  if (e >= nnz) return;
  int k = blockIdx.x & (kCopies - 1);
  atomicAdd(&cnt8[k * kN + rows[e]], 1);
}

// ---------------- scan over summed copies ----------------------------------
constexpr int kScanChunk = 2048;   // 256 threads x 8 elems
constexpr int kScanBlk   = (kN + kScanChunk - 1) / kScanChunk;  // 49

__global__ void scan1_kernel(const int* __restrict__ cnt8, int* __restrict__ rowptr,
                             int* __restrict__ partials, int n) {
  __shared__ int sd[256];
  int b = blockIdx.x, t = threadIdx.x;
  int base = b * kScanChunk + t * 8;
  int v[8]; int s = 0;
  #pragma unroll
  for (int k = 0; k < 8; ++k) {
    int idx = base + k;
    int c = 0;
    if (idx < n) {
      #pragma unroll
      for (int j = 0; j < kCopies; ++j) c += cnt8[j * kN + idx];
    }
    v[k] = c; s += c;
  }
  sd[t] = s; __syncthreads();
  #pragma unroll
  for (int off = 1; off < 256; off <<= 1) {
    int x = (t >= off) ? sd[t - off] : 0;
    __syncthreads();
    sd[t] += x;
    __syncthreads();
  }
  if (t == 255) partials[b] = sd[255];
  int run = (t == 0) ? 0 : sd[t - 1];
  #pragma unroll
  for (int k = 0; k < 8; ++k) { int idx = base + k; if (idx < n) rowptr[idx] = run; run += v[k]; }
}

__global__ void scan2_kernel(int* __restrict__ partials, int* __restrict__ rowptr,
                             int nblk, int n) {
  __shared__ int sd[64];
  int t = threadIdx.x;
  sd[t] = (t < nblk) ? partials[t] : 0;
  __syncthreads();
  #pragma unroll
  for (int off = 1; off < 64; off <<= 1) {
    int x = (t >= off) ? sd[t - off] : 0;
    __syncthreads();
    sd[t] += x;
    __syncthreads();
  }
  if (t < nblk) partials[t] = (t == 0) ? 0 : sd[t - 1];
  if (t == 63) rowptr[n] = sd[63];
}

// finalize rowptr; seed cur = rowptr; seed coarse bucket cursors
__global__ void scan3_kernel(int* __restrict__ rowptr, int* __restrict__ cur,
                             int* __restrict__ bcur,
                             const int* __restrict__ partials, int n) {
  int i = blockIdx.x * blockDim.x + threadIdx.x;
  if (i < n) {
    int v = rowptr[i] + partials[i / kScanChunk];
    rowptr[i] = v;
    cur[i] = v;
    if ((i % kBktRows) == 0) bcur[i / kBktRows] = v;
  }
}

// ---------------- passA: partition adj edges into 8 row-buckets ------------
// Block-level reservation (LDS int counts, native ds_add - proven r10) +
// 8 global cursor atomics per block. Each block appends a contiguous chunk
// -> full-line writes. Record: P.x = rowlocal<<17 | col, P.y = f32 val bits.
__global__ void __launch_bounds__(256) passA_kernel(
    const int* __restrict__ rows, const int* __restrict__ cols,
    const float* __restrict__ vals, int* __restrict__ bcur,
    uint2* __restrict__ P, int nnz) {
  __shared__ int lcnt[8];
  __shared__ int gbase[8];
  const int tid = threadIdx.x;
  const int base = blockIdx.x * 4096;
  if (tid < 8) lcnt[tid] = 0;
  __syncthreads();
  // phase 1: per-thread register counters (static names, rule #20)
  int c0 = 0, c1 = 0, c2 = 0, c3 = 0, c4 = 0, c5 = 0, c6 = 0, c7 = 0;
  for (int i = 0; i < 16; ++i) {
    int e = base + i * 256 + tid;
    if (e < nnz) {
      int b = rows[e] / kBktRows;
      if (b < 4) {
        if (b < 2) { if (b == 0) c0++; else c1++; }
        else       { if (b == 2) c2++; else c3++; }
      } else {
        if (b < 6) { if (b == 4) c4++; else c5++; }
        else       { if (b == 6) c6++; else c7++; }
      }
    }
  }
  if (c0) atomicAdd(&lcnt[0], c0);
  if (c1) atomicAdd(&lcnt[1], c1);
  if (c2) atomicAdd(&lcnt[2], c2);
  if (c3) atomicAdd(&lcnt[3], c3);
  if (c4) atomicAdd(&lcnt[4], c4);
  if (c5) atomicAdd(&lcnt[5], c5);
  if (c6) atomicAdd(&lcnt[6], c6);
  if (c7) atomicAdd(&lcnt[7], c7);
  __syncthreads();
  if (tid < 8) {
    gbase[tid] = atomicAdd(&bcur[tid], lcnt[tid]);
    lcnt[tid] = 0;   // reuse as intra-block cursor
  }
  __syncthreads();
  // phase 2: append
  for (int i = 0; i < 16; ++i) {
    int e = base + i * 256 + tid;
    if (e >= nnz) continue;
    int r = rows[e];
    int b = r / kBktRows;
    int lpos = atomicAdd(&lcnt[b], 1);
    uint2 rec;
    rec.x = ((uint32_t)(r % kBktRows) << 17) | (uint32_t)cols[e];
    rec.y = __float_as_uint(vals[e]);
    P[gbase[b] + lpos] = rec;
  }
}

// ---------------- passB: fine scatter, bucket pinned to one XCD ------------
// bucket = blockIdx & 7 (r11-proven round-robin XCD mapping): all atomics on
// this bucket's cursors AND all stores into its 1.6MB spack window come from
// one XCD -> lines stay in that XCD's L2 until full.
__global__ void passB_kernel(const int* __restrict__ rowptr,
                             const uint2* __restrict__ P,
                             int* __restrict__ cur,
                             uint32_t* __restrict__ spack) {
  const int k = blockIdx.x & 7;
  const int slot = blockIdx.x >> 3;
  const int nslots = gridDim.x >> 3;
  const int lorow = k * kBktRows;
  const int s = rowptr[lorow];
  const int t = rowptr[lorow + kBktRows];
  for (int idx = s + slot * 256 + threadIdx.x; idx < t; idx += nslots * 256) {
    uint2 rec = P[idx];
    int r = lorow + (int)(rec.x >> 17);
    int pos = atomicAdd(&cur[r], 1);
    float v = __uint_as_float(rec.y);
    uint32_t h = (uint32_t)__half_as_ushort(__float2half_rn(v)) & 0x7FFFu;
    spack[pos] = ((rec.x & 0x1FFFFu) << 15) | h;
  }
}

// ---------------- CSR SpMM over 4B records, 8-deep unroll (r15/r16) --------
template<bool RELU>
__global__ void spmm_csr_kernel(const int* __restrict__ rowptr,
                                const uint32_t* __restrict__ spack,
                                const uint16_t* __restrict__ B,  // bf16 [*, kDOut]
                                float* __restrict__ outv, int nrows) {
  int tid = threadIdx.x;
  int row = blockIdx.x * 4 + (tid >> 6);
  int lane = tid & 63;
  if (row >= nrows) return;
  int e = rowptr[row], e_end = rowptr[row + 1];
  float a0 = 0.0f, a1 = 0.0f;
  const int doff = lane * 2;
  auto dec = [](uint32_t p) -> float {
    return __half2float(__ushort_as_half((unsigned short)(p & 0x7FFFu)));
  };
  for (; e + 7 < e_end; e += 8) {
    uint32_t p0 = spack[e],     p1 = spack[e + 1];
    uint32_t p2 = spack[e + 2], p3 = spack[e + 3];
    uint32_t p4 = spack[e + 4], p5 = spack[e + 5];
    uint32_t p6 = spack[e + 6], p7 = spack[e + 7];
    uint32_t g0 = *(const uint32_t*)(B + (size_t)(p0 >> 15) * kDOut + doff);
    uint32_t g1 = *(const uint32_t*)(B + (size_t)(p1 >> 15) * kDOut + doff);
    uint32_t g2 = *(const uint32_t*)(B + (size_t)(p2 >> 15) * kDOut + doff);
    uint32_t g3 = *(const uint32_t*)(B + (size_t)(p3 >> 15) * kDOut + doff);
    uint32_t g4 = *(const uint32_t*)(B + (size_t)(p4 >> 15) * kDOut + doff);
    uint32_t g5 = *(const uint32_t*)(B + (size_t)(p5 >> 15) * kDOut + doff);
    uint32_t g6 = *(const uint32_t*)(B + (size_t)(p6 >> 15) * kDOut + doff);
    uint32_t g7 = *(const uint32_t*)(B + (size_t)(p7 >> 15) * kDOut + doff);
    float v0 = dec(p0), v1 = dec(p1), v2 = dec(p2), v3 = dec(p3);
    float v4 = dec(p4), v5 = dec(p5), v6 = dec(p6), v7 = dec(p7);
    a0 += v0 * bf16lo_to_f32(g0); a1 += v0 * bf16hi_to_f32(g0);
    a0 += v1 * bf16lo_to_f32(g1); a1 += v1 * bf16hi_to_f32(g1);
    a0 += v2 * bf16lo_to_f32(g2); a1 += v2 * bf16hi_to_f32(g2);
    a0 += v3 * bf16lo_to_f32(g3); a1 += v3 * bf16hi_to_f32(g3);
    a0 += v4 * bf16lo_to_f32(g4); a1 += v4 * bf16hi_to_f32(g4);
    a0 += v5 * bf16lo_to_f32(g5); a1 += v5 * bf16hi_to_f32(g5);
    a0 += v6 * bf16lo_to_f32(g6); a1 += v6 * bf16hi_to_f32(g6);
    a0 += v7 * bf16lo_to_f32(g7); a1 += v7 * bf16hi_to_f32(g7);
  }
  for (; e < e_end; ++e) {
    uint32_t p0 = spack[e];
    float v0 = dec(p0);
    uint32_t g0 = *(const uint32_t*)(B + (size_t)(p0 >> 15) * kDOut + doff);
    a0 += v0 * bf16lo_to_f32(g0);
    a1 += v0 * bf16hi_to_f32(g0);
  }
  if (RELU) { a0 = fmaxf(a0, 0.0f); a1 = fmaxf(a1, 0.0f); }
  float2 o; o.x = a0; o.y = a1;
  ((float2*)outv)[(size_t)row * (kDOut / 2) + lane] = o;
}

// ---------------------------------------------------------------------------
extern "C" void kernel_launch(void* const* d_in, const int* in_sizes, int n_in,
                              void* d_out, int out_size, void* d_ws, size_t ws_size,
                              hipStream_t stream) {
  const int*   x_rows   = (const int*)d_in[0];
  const int*   x_cols   = (const int*)d_in[1];
  const float* x_vals   = (const float*)d_in[2];
  const int*   adj_rows = (const int*)d_in[3];
  const int*   adj_cols = (const int*)d_in[4];
  const float* adj_vals = (const float*)d_in[5];
  const float* W        = (const float*)d_in[6];
  float* out = (float*)d_out;

  // workspace layout (256B-aligned chunks)
  size_t off = 0;
  auto take = [&](size_t bytes) -> char* {
    char* p = (char*)d_ws + off;
    off += (bytes + 255) & ~(size_t)255;
    return p;
  };
  uint16_t* hb     = (uint16_t*)take((size_t)kN * kDOut * 2);         // 25.6 MB
  uint32_t* Wt     = (uint32_t*)take((size_t)kDIn * kDOut / 2 * 4);   // 64 KB
  int*      rowptr = (int*)take((size_t)(kN + 1) * 4);                // 400 KB
  int*      cnt8   = (int*)take((size_t)kCopies * kN * 4);            // 3.2 MB
  int*      cur    = (int*)take((size_t)kN * 4);                      // 400 KB
  int*      bcur   = (int*)take(8 * 4);
  int*      partials = (int*)take(64 * 4);
  uint32_t* spack  = (uint32_t*)take((size_t)kNNZ * 4);               // 12.8 MB
  float*    Xd     = (float*)take((size_t)kN * kDIn * 4);             // 102.4 MB
  const size_t needed = off;                                          // ~145 MB
  if (ws_size < needed) return;  // ws proven >= 157.7 MB (r12-r16 ran this path)
  uint2*    P = (uint2*)Xd;  // 25.6 MB, aliases Xd (adj phase runs after gemm)

  const int edgeBlocks = (kNNZ + 255) / 256;
  const int spmmBlocks = (kN + 3) / 4;
  const int gemmBlocks = (kN / 16 + 3) / 4;   // 1563
  const int passABlocks = (kNNZ + 4095) / 4096;   // 782
  const int passBBlocks = 8 * 1664;               // 8 buckets x 1664 slots

  wpack_frag_kernel<<<(kDIn * kDOut / 2 + 255) / 256, 256, 0, stream>>>(W, Wt);

  // ---------- X: dense scatter-add + MFMA gemm -> hb (bf16) ----------
  hipMemsetAsync(Xd, 0, (size_t)kN * kDIn * 4, stream);
  scatteradd_kernel<<<edgeBlocks, 256, 0, stream>>>(x_rows, x_cols, x_vals, Xd, kNNZ);
  gemm_mfma_kernel<<<gemmBlocks, 256, 0, stream>>>(Xd, Wt, hb);

  // ---------- adj: hist8 + scan + passA/passB scatter + spmm2(+relu) -------
  hipMemsetAsync(cnt8, 0, (size_t)kCopies * kN * 4, stream);
  hist8_kernel<<<edgeBlocks, 256, 0, stream>>>(adj_rows, cnt8, kNNZ);
  scan1_kernel<<<kScanBlk, 256, 0, stream>>>(cnt8, rowptr, partials, kN);
  scan2_kernel<<<1, 64, 0, stream>>>(partials, rowptr, kScanBlk, kN);
  scan3_kernel<<<(kN + 255) / 256, 256, 0, stream>>>(rowptr, cur, bcur, partials, kN);
  passA_kernel<<<passABlocks, 256, 0, stream>>>(
      adj_rows, adj_cols, adj_vals, bcur, P, kNNZ);
  passB_kernel<<<passBBlocks, 256, 0, stream>>>(rowptr, P, cur, spack);
  spmm_csr_kernel<true><<<spmmBlocks, 256, 0, stream>>>(
      rowptr, spack, hb, out, kN);
}

// Round 18
// 608.976 us; speedup vs baseline: 1.8983x; 1.0268x over previous
//
#include <hip/hip_runtime.h>
#include <hip/hip_fp16.h>
#include <hip/hip_bf16.h>
#include <stdint.h>

constexpr int kN    = 100000;   // nodes
constexpr int kDOut = 128;      // output dim
constexpr int kDIn  = 256;      // input feature dim
constexpr int kNNZ  = 3200000;  // nnz for both X and A
constexpr float kInvKeep = (float)(1.0 / 0.9);
constexpr int kCopies  = 8;     // XCD privatization (proven r11/r13)
constexpr int kBktRows = kN / 8;   // 12500 rows per coarse bucket

typedef __attribute__((ext_vector_type(8))) short short8v;  // 8 bf16 (4 VGPR)
typedef __attribute__((ext_vector_type(4))) float f32x4;    // MFMA C/D

// ---------------- RNG (verified round 4: partitionable, bits = o0^o1) -----
__device__ __forceinline__ uint32_t rotl32(uint32_t v, int r) {
  return (v << r) | (v >> (32 - r));
}
__device__ __forceinline__ void threefry2x32(uint32_t k0, uint32_t k1,
                                             uint32_t x0, uint32_t x1,
                                             uint32_t& o0, uint32_t& o1) {
  const uint32_t ks0 = k0, ks1 = k1, ks2 = k0 ^ k1 ^ 0x1BD11BDAu;
  x0 += ks0; x1 += ks1;
#define TF_RND(r) { x0 += x1; x1 = rotl32(x1, (r)); x1 ^= x0; }
  TF_RND(13) TF_RND(15) TF_RND(26) TF_RND(6)
  x0 += ks1; x1 += ks2 + 1u;
  TF_RND(17) TF_RND(29) TF_RND(16) TF_RND(24)
  x0 += ks2; x1 += ks0 + 2u;
  TF_RND(13) TF_RND(15) TF_RND(26) TF_RND(6)
  x0 += ks0; x1 += ks1 + 3u;
  TF_RND(17) TF_RND(29) TF_RND(16) TF_RND(24)
  x0 += ks1; x1 += ks2 + 4u;
  TF_RND(13) TF_RND(15) TF_RND(26) TF_RND(6)
  x0 += ks2; x1 += ks0 + 5u;
#undef TF_RND
  o0 = x0; o1 = x1;
}
__device__ __forceinline__ float keep_mask(uint32_t i) {
  uint32_t o0, o1;
  threefry2x32(0u, 42u, 0u, i, o0, o1);
  uint32_t bits = o0 ^ o1;
  float u = __uint_as_float((bits >> 9) | 0x3f800000u) - 1.0f;
  return floorf(0.9f + u);
}

// ---------------- bf16 helpers (RTNE) --------------------------------------
__device__ __forceinline__ uint32_t f32_to_bf16(float f) {
  uint32_t u = __float_as_uint(f);
  u += 0x7fffu + ((u >> 16) & 1u);
  return u >> 16;
}
__device__ __forceinline__ float bf16lo_to_f32(uint32_t packed) {
  return __uint_as_float(packed << 16);
}
__device__ __forceinline__ float bf16hi_to_f32(uint32_t packed) {
  return __uint_as_float(packed & 0xffff0000u);
}

// ---------------- W -> MFMA B-fragment order (verified r16) ----------------
__global__ void wpack_frag_kernel(const float* __restrict__ W,
                                  uint32_t* __restrict__ Wt) {
  int i = blockIdx.x * blockDim.x + threadIdx.x;
  if (i >= kDIn * kDOut / 2) return;   // 16384
  int jj   = i & 3;
  int lane = (i >> 2) & 63;
  int ks   = (i >> 8) & 7;
  int nt   = i >> 11;
  int n = nt * 16 + (lane & 15);
  int k = ks * 32 + ((lane >> 4) * 8) + 2 * jj;
  uint32_t lo = f32_to_bf16(W[(size_t)k * kDOut + n]);
  uint32_t hi = f32_to_bf16(W[(size_t)(k + 1) * kDOut + n]);
  Wt[i] = lo | (hi << 16);
}

// ---------------- X dense path: bf16 Xd + pk-bf16 atomics ------------------
// gfx950 GLOBAL_ATOMIC_PK_ADD_BF16 via unsafeAtomicAdd(__hip_bfloat162*).
// Xd footprint halves (51.2 MB) -> better L2 residency for the random RMWs.
__global__ void scatteradd_kernel(const int* __restrict__ rows,
                                  const int* __restrict__ cols,
                                  const float* __restrict__ vals,
                                  __hip_bfloat162* __restrict__ Xd2, int nnz) {
  int e = blockIdx.x * blockDim.x + threadIdx.x;
  if (e >= nnz) return;
  if (keep_mask((uint32_t)e) == 0.0f) return;
  int r = rows[e], c = cols[e];
  float v = vals[e] * kInvKeep;
  uint32_t pk = f32_to_bf16(v) << ((c & 1) ? 16 : 0);  // other half = +0.0
  __hip_bfloat162 val = *reinterpret_cast<__hip_bfloat162*>(&pk);
  unsafeAtomicAdd(&Xd2[((size_t)r * kDIn + c) >> 1], val);
}

// Wave computes 16 rows x 128 cols: 8 ksteps x 8 ntile MFMAs (16x16x32 bf16).
// A now loads bf16 Xd directly (one 16B load per kstep, no cvt chain).
__global__ void __launch_bounds__(256) gemm_mfma_kernel(
    const uint16_t* __restrict__ Xd, const uint32_t* __restrict__ Wt,
    uint16_t* __restrict__ hb) {
  const int tid = threadIdx.x;
  const int gw = blockIdx.x * 4 + (tid >> 6);
  if (gw >= kN / 16) return;
  const int lane = tid & 63;
  const int row16 = gw * 16;
  const uint16_t* xrow =
      Xd + (size_t)(row16 + (lane & 15)) * kDIn + ((lane >> 4) * 8);

  f32x4 acc[8];
  #pragma unroll
  for (int nt = 0; nt < 8; ++nt) acc[nt] = f32x4{0.f, 0.f, 0.f, 0.f};

  #pragma unroll
  for (int ks = 0; ks < 8; ++ks) {
    short8v a = *(const short8v*)(xrow + ks * 32);
    const uint32_t* bbase = Wt + ks * 256 + lane * 4;
    #pragma unroll
    for (int nt = 0; nt < 8; ++nt) {
      short8v b = *(const short8v*)(bbase + nt * 2048);
      acc[nt] = __builtin_amdgcn_mfma_f32_16x16x32_bf16(a, b, acc[nt], 0, 0, 0);
    }
  }

  const int r0 = row16 + (lane >> 4) * 4;
  const int c0 = lane & 15;
  #pragma unroll
  for (int nt = 0; nt < 8; ++nt) {
    #pragma unroll
    for (int rg = 0; rg < 4; ++rg) {
      hb[(size_t)(r0 + rg) * kDOut + nt * 16 + c0] =
          (uint16_t)f32_to_bf16(acc[nt][rg]);
    }
  }
}

// ---------------- XCD-privatized histogram (proven r11/r13) ----------------
__global__ void hist8_kernel(const int* __restrict__ rows, int* __restrict__ cnt8,
                             int nnz) {
  int e = blockIdx.x * blockDim.x + threadIdx.x;
  if (e >= nnz) return;
  int k = blockIdx.x & (kCopies - 1);
  atomicAdd(&cnt8[k * kN + rows[e]], 1);
}

// ---------------- scan over summed copies ----------------------------------
constexpr int kScanChunk = 2048;   // 256 threads x 8 elems
constexpr int kScanBlk   = (kN + kScanChunk - 1) / kScanChunk;  // 49

__global__ void scan1_kernel(const int* __restrict__ cnt8, int* __restrict__ rowptr,
                             int* __restrict__ partials, int n) {
  __shared__ int sd[256];
  int b = blockIdx.x, t = threadIdx.x;
  int base = b * kScanChunk + t * 8;
  int v[8]; int s = 0;
  #pragma unroll
  for (int k = 0; k < 8; ++k) {
    int idx = base + k;
    int c = 0;
    if (idx < n) {
      #pragma unroll
      for (int j = 0; j < kCopies; ++j) c += cnt8[j * kN + idx];
    }
    v[k] = c; s += c;
  }
  sd[t] = s; __syncthreads();
  #pragma unroll
  for (int off = 1; off < 256; off <<= 1) {
    int x = (t >= off) ? sd[t - off] : 0;
    __syncthreads();
    sd[t] += x;
    __syncthreads();
  }
  if (t == 255) partials[b] = sd[255];
  int run = (t == 0) ? 0 : sd[t - 1];
  #pragma unroll
  for (int k = 0; k < 8; ++k) { int idx = base + k; if (idx < n) rowptr[idx] = run; run += v[k]; }
}

__global__ void scan2_kernel(int* __restrict__ partials, int* __restrict__ rowptr,
                             int nblk, int n) {
  __shared__ int sd[64];
  int t = threadIdx.x;
  sd[t] = (t < nblk) ? partials[t] : 0;
  __syncthreads();
  #pragma unroll
  for (int off = 1; off < 64; off <<= 1) {
    int x = (t >= off) ? sd[t - off] : 0;
    __syncthreads();
    sd[t] += x;
    __syncthreads();
  }
  if (t < nblk) partials[t] = (t == 0) ? 0 : sd[t - 1];
  if (t == 63) rowptr[n] = sd[63];
}

// finalize rowptr; seed cur = rowptr; seed coarse bucket cursors
__global__ void scan3_kernel(int* __restrict__ rowptr, int* __restrict__ cur,
                             int* __restrict__ bcur,
                             const int* __restrict__ partials, int n) {
  int i = blockIdx.x * blockDim.x + threadIdx.x;
  if (i < n) {
    int v = rowptr[i] + partials[i / kScanChunk];
    rowptr[i] = v;
    cur[i] = v;
    if ((i % kBktRows) == 0) bcur[i / kBktRows] = v;
  }
}

// ---------------- passA: partition adj edges into 8 row-buckets (r17) ------
__global__ void __launch_bounds__(256) passA_kernel(
    const int* __restrict__ rows, const int* __restrict__ cols,
    const float* __restrict__ vals, int* __restrict__ bcur,
    uint2* __restrict__ P, int nnz) {
  __shared__ int lcnt[8];
  __shared__ int gbase[8];
  const int tid = threadIdx.x;
  const int base = blockIdx.x * 4096;
  if (tid < 8) lcnt[tid] = 0;
  __syncthreads();
  int c0 = 0, c1 = 0, c2 = 0, c3 = 0, c4 = 0, c5 = 0, c6 = 0, c7 = 0;
  for (int i = 0; i < 16; ++i) {
    int e = base + i * 256 + tid;
    if (e < nnz) {
      int b = rows[e] / kBktRows;
      if (b < 4) {
        if (b < 2) { if (b == 0) c0++; else c1++; }
        else       { if (b == 2) c2++; else c3++; }
      } else {
        if (b < 6) { if (b == 4) c4++; else c5++; }
        else       { if (b == 6) c6++; else c7++; }
      }
    }
  }
  if (c0) atomicAdd(&lcnt[0], c0);
  if (c1) atomicAdd(&lcnt[1], c1);
  if (c2) atomicAdd(&lcnt[2], c2);
  if (c3) atomicAdd(&lcnt[3], c3);
  if (c4) atomicAdd(&lcnt[4], c4);
  if (c5) atomicAdd(&lcnt[5], c5);
  if (c6) atomicAdd(&lcnt[6], c6);
  if (c7) atomicAdd(&lcnt[7], c7);
  __syncthreads();
  if (tid < 8) {
    gbase[tid] = atomicAdd(&bcur[tid], lcnt[tid]);
    lcnt[tid] = 0;
  }
  __syncthreads();
  for (int i = 0; i < 16; ++i) {
    int e = base + i * 256 + tid;
    if (e >= nnz) continue;
    int r = rows[e];
    int b = r / kBktRows;
    int lpos = atomicAdd(&lcnt[b], 1);
    uint2 rec;
    rec.x = ((uint32_t)(r % kBktRows) << 17) | (uint32_t)cols[e];
    rec.y = __float_as_uint(vals[e]);
    P[gbase[b] + lpos] = rec;
  }
}

// ---------------- passB: fine scatter, bucket pinned to one XCD (r17) ------
__global__ void passB_kernel(const int* __restrict__ rowptr,
                             const uint2* __restrict__ P,
                             int* __restrict__ cur,
                             uint32_t* __restrict__ spack) {
  const int k = blockIdx.x & 7;
  const int slot = blockIdx.x >> 3;
  const int nslots = gridDim.x >> 3;
  const int lorow = k * kBktRows;
  const int s = rowptr[lorow];
  const int t = rowptr[lorow + kBktRows];
  for (int idx = s + slot * 256 + threadIdx.x; idx < t; idx += nslots * 256) {
    uint2 rec = P[idx];
    int r = lorow + (int)(rec.x >> 17);
    int pos = atomicAdd(&cur[r], 1);
    float v = __uint_as_float(rec.y);
    uint32_t h = (uint32_t)__half_as_ushort(__float2half_rn(v)) & 0x7FFFu;
    spack[pos] = ((rec.x & 0x1FFFFu) << 15) | h;
  }
}

// ---------------- CSR SpMM over 4B records, 8-deep unroll (r15/r16) --------
template<bool RELU>
__global__ void spmm_csr_kernel(const int* __restrict__ rowptr,
                                const uint32_t* __restrict__ spack,
                                const uint16_t* __restrict__ B,  // bf16 [*, kDOut]
                                float* __restrict__ outv, int nrows) {
  int tid = threadIdx.x;
  int row = blockIdx.x * 4 + (tid >> 6);
  int lane = tid & 63;
  if (row >= nrows) return;
  int e = rowptr[row], e_end = rowptr[row + 1];
  float a0 = 0.0f, a1 = 0.0f;
  const int doff = lane * 2;
  auto dec = [](uint32_t p) -> float {
    return __half2float(__ushort_as_half((unsigned short)(p & 0x7FFFu)));
  };
  for (; e + 7 < e_end; e += 8) {
    uint32_t p0 = spack[e],     p1 = spack[e + 1];
    uint32_t p2 = spack[e + 2], p3 = spack[e + 3];
    uint32_t p4 = spack[e + 4], p5 = spack[e + 5];
    uint32_t p6 = spack[e + 6], p7 = spack[e + 7];
    uint32_t g0 = *(const uint32_t*)(B + (size_t)(p0 >> 15) * kDOut + doff);
    uint32_t g1 = *(const uint32_t*)(B + (size_t)(p1 >> 15) * kDOut + doff);
    uint32_t g2 = *(const uint32_t*)(B + (size_t)(p2 >> 15) * kDOut + doff);
    uint32_t g3 = *(const uint32_t*)(B + (size_t)(p3 >> 15) * kDOut + doff);
    uint32_t g4 = *(const uint32_t*)(B + (size_t)(p4 >> 15) * kDOut + doff);
    uint32_t g5 = *(const uint32_t*)(B + (size_t)(p5 >> 15) * kDOut + doff);
    uint32_t g6 = *(const uint32_t*)(B + (size_t)(p6 >> 15) * kDOut + doff);
    uint32_t g7 = *(const uint32_t*)(B + (size_t)(p7 >> 15) * kDOut + doff);
    float v0 = dec(p0), v1 = dec(p1), v2 = dec(p2), v3 = dec(p3);
    float v4 = dec(p4), v5 = dec(p5), v6 = dec(p6), v7 = dec(p7);
    a0 += v0 * bf16lo_to_f32(g0); a1 += v0 * bf16hi_to_f32(g0);
    a0 += v1 * bf16lo_to_f32(g1); a1 += v1 * bf16hi_to_f32(g1);
    a0 += v2 * bf16lo_to_f32(g2); a1 += v2 * bf16hi_to_f32(g2);
    a0 += v3 * bf16lo_to_f32(g3); a1 += v3 * bf16hi_to_f32(g3);
    a0 += v4 * bf16lo_to_f32(g4); a1 += v4 * bf16hi_to_f32(g4);
    a0 += v5 * bf16lo_to_f32(g5); a1 += v5 * bf16hi_to_f32(g5);
    a0 += v6 * bf16lo_to_f32(g6); a1 += v6 * bf16hi_to_f32(g6);
    a0 += v7 * bf16lo_to_f32(g7); a1 += v7 * bf16hi_to_f32(g7);
  }
  for (; e < e_end; ++e) {
    uint32_t p0 = spack[e];
    float v0 = dec(p0);
    uint32_t g0 = *(const uint32_t*)(B + (size_t)(p0 >> 15) * kDOut + doff);
    a0 += v0 * bf16lo_to_f32(g0);
    a1 += v0 * bf16hi_to_f32(g0);
  }
  if (RELU) { a0 = fmaxf(a0, 0.0f); a1 = fmaxf(a1, 0.0f); }
  float2 o; o.x = a0; o.y = a1;
  ((float2*)outv)[(size_t)row * (kDOut / 2) + lane] = o;
}

// ---------------------------------------------------------------------------
extern "C" void kernel_launch(void* const* d_in, const int* in_sizes, int n_in,
                              void* d_out, int out_size, void* d_ws, size_t ws_size,
                              hipStream_t stream) {
  const int*   x_rows   = (const int*)d_in[0];
  const int*   x_cols   = (const int*)d_in[1];
  const float* x_vals   = (const float*)d_in[2];
  const int*   adj_rows = (const int*)d_in[3];
  const int*   adj_cols = (const int*)d_in[4];
  const float* adj_vals = (const float*)d_in[5];
  const float* W        = (const float*)d_in[6];
  float* out = (float*)d_out;

  // workspace layout (256B-aligned chunks)
  size_t off = 0;
  auto take = [&](size_t bytes) -> char* {
    char* p = (char*)d_ws + off;
    off += (bytes + 255) & ~(size_t)255;
    return p;
  };
  uint16_t* hb     = (uint16_t*)take((size_t)kN * kDOut * 2);         // 25.6 MB
  uint32_t* Wt     = (uint32_t*)take((size_t)kDIn * kDOut / 2 * 4);   // 64 KB
  int*      rowptr = (int*)take((size_t)(kN + 1) * 4);                // 400 KB
  int*      cnt8   = (int*)take((size_t)kCopies * kN * 4);            // 3.2 MB
  int*      cur    = (int*)take((size_t)kN * 4);                      // 400 KB
  int*      bcur   = (int*)take(8 * 4);
  int*      partials = (int*)take(64 * 4);
  uint32_t* spack  = (uint32_t*)take((size_t)kNNZ * 4);               // 12.8 MB
  uint16_t* Xd     = (uint16_t*)take((size_t)kN * kDIn * 2);          // 51.2 MB
  const size_t needed = off;                                          // ~94 MB
  if (ws_size < needed) return;  // ws proven >= 157.7 MB (r12-r17)
  uint2*    P = (uint2*)Xd;  // 25.6 MB, aliases Xd (adj phase runs after gemm)

  const int edgeBlocks = (kNNZ + 255) / 256;
  const int spmmBlocks = (kN + 3) / 4;
  const int gemmBlocks = (kN / 16 + 3) / 4;   // 1563
  const int passABlocks = (kNNZ + 4095) / 4096;   // 782
  const int passBBlocks = 8 * 1664;               // 8 buckets x 1664 slots

  wpack_frag_kernel<<<(kDIn * kDOut / 2 + 255) / 256, 256, 0, stream>>>(W, Wt);

  // ---------- X: bf16 dense scatter-add (pk atomics) + MFMA gemm -> hb -----
  hipMemsetAsync(Xd, 0, (size_t)kN * kDIn * 2, stream);
  scatteradd_kernel<<<edgeBlocks, 256, 0, stream>>>(
      x_rows, x_cols, x_vals, (__hip_bfloat162*)Xd, kNNZ);
  gemm_mfma_kernel<<<gemmBlocks, 256, 0, stream>>>(Xd, Wt, hb);

  // ---------- adj: hist8 + scan + passA/passB scatter + spmm2(+relu) -------
  hipMemsetAsync(cnt8, 0, (size_t)kCopies * kN * 4, stream);
  hist8_kernel<<<edgeBlocks, 256, 0, stream>>>(adj_rows, cnt8, kNNZ);
  scan1_kernel<<<kScanBlk, 256, 0, stream>>>(cnt8, rowptr, partials, kN);
  scan2_kernel<<<1, 64, 0, stream>>>(partials, rowptr, kScanBlk, kN);
  scan3_kernel<<<(kN + 255) / 256, 256, 0, stream>>>(rowptr, cur, bcur, partials, kN);
  passA_kernel<<<passABlocks, 256, 0, stream>>>(
      adj_rows, adj_cols, adj_vals, bcur, P, kNNZ);
  passB_kernel<<<passBBlocks, 256, 0, stream>>>(rowptr, P, cur, spack);
  spmm_csr_kernel<true><<<spmmBlocks, 256, 0, stream>>>(
      rowptr, spack, hb, out, kN);
}